// Round 8
// baseline (1966.783 us; speedup 1.0000x reference)
//
#include <hip/hip_runtime.h>
#include <hip/hip_fp16.h>

#define DT 5e-5f
#define SPRING_Y 30000.0f
#define DASHPOT 100.0f
// exp(-DT * DRAG_DAMPING) = exp(-5e-5)
#define DRAG 0.9999500012499792f
#define NSUB 100

// R18 = R17's request-count structure (1 gather/eval, uint2 lane-owned adj)
// with SENTINEL-escaped velocity packing. R17 failed (absmax 0.39) because
// floor-slammed vertices (z0<0 tail snapped to z=0 -> springs stretched O(1)
// -> stiff oscillation, |v| up to tens) saturated the +-2 pack range.
// Fix: pack range +-0.25 (res 4.9e-4, 8x finer); any |v|>0.249 stores
// sentinel w=0x80000000 (bit31 never set by natural packs, max 0x3FFFFFFF);
// readers of a sentinel w gather the exact fp32 velocity from the V array
// (exec-masked: only sentinel lanes issue the extra request, ~0.1-3%).
// Fast vertices are exact; slow ones carry <=4.9e-4 quantization -> both
// safe. adj = CSR, rows padded to 16 entries; entry:
// (nbr:17)<<15 | fp16(1/rest)&0x7fff. Lane s owns entries 16u+2s..+1 ->
// one uint2 per 2 evals; wave's 8 lanes touch one 64B adj line/vertex-iter.

// ---------- packed-velocity helpers ----------

__device__ __forceinline__ float packv(float x, float y, float z) {
    if (fmaxf(fmaxf(fabsf(x), fabsf(y)), fabsf(z)) > 0.249f)
        return __uint_as_float(0x80000000u);          // sentinel: exact path
    unsigned qx = (unsigned)(x * 2048.0f + 512.5f);   // range check bounds q
    unsigned qy = (unsigned)(y * 2048.0f + 512.5f);
    unsigned qz = (unsigned)(z * 2048.0f + 512.5f);
    return __uint_as_float((qx << 20) | (qy << 10) | qz);
}

__device__ __forceinline__ float3 getvel(float w, const float4* __restrict__ V,
                                         int n) {
    unsigned uw = __float_as_uint(w);
    if (uw & 0x80000000u) {                           // rare: exact fp32 gather
        float4 vf = V[n];
        return make_float3(vf.x, vf.y, vf.z);
    }
    float3 v;
    v.x = (float)((int)((uw >> 20) & 1023u) - 512) * (1.0f / 2048.0f);
    v.y = (float)((int)((uw >> 10) & 1023u) - 512) * (1.0f / 2048.0f);
    v.z = (float)((int)( uw        & 1023u) - 512) * (1.0f / 2048.0f);
    return v;
}

// ---------- build ----------

__global__ void init_k(const float* __restrict__ x0, float4* __restrict__ G,
                       float4* __restrict__ V, int* __restrict__ deg, int nv) {
    int i = blockIdx.x * blockDim.x + threadIdx.x;
    if (i < nv) {
        G[i] = make_float4(x0[3 * i], x0[3 * i + 1], x0[3 * i + 2],
                           packv(0.f, 0.f, 0.f));
        V[i] = make_float4(0.f, 0.f, 0.f, 0.f);
        deg[i] = 0;
    }
}

// degree count: atomics over 100K addresses (low contention)
__global__ void count_k(const int2* __restrict__ springs, int* __restrict__ deg,
                        int ns) {
    int s = blockIdx.x * blockDim.x + threadIdx.x;
    if (s >= ns) return;
    int2 p = springs[s];
    atomicAdd(&deg[p.x], 1);
    atomicAdd(&deg[p.y], 1);
}

// exclusive scan of PADDED degree (ceil16) -> rowstart; 3 phases
__global__ void scan1_k(const int* __restrict__ deg, int* __restrict__ rowstart,
                        int* __restrict__ bsum, int nv) {
    __shared__ int sh[256];
    int t = threadIdx.x;
    int i = blockIdx.x * 256 + t;
    int v = (i < nv) ? ((deg[i] + 15) & ~15) : 0;
    sh[t] = v;
    __syncthreads();
    for (int off = 1; off < 256; off <<= 1) {      // Hillis-Steele inclusive
        int add = (t >= off) ? sh[t - off] : 0;
        __syncthreads();
        sh[t] += add;
        __syncthreads();
    }
    if (i < nv) rowstart[i] = sh[t] - v;           // local exclusive
    if (t == 255) bsum[blockIdx.x] = sh[255];      // block total
}

// parallel scan of block sums (nb <= 512)
__global__ void scan2_k(int* __restrict__ bsum, int nb) {
    __shared__ int sh[512];
    int t = threadIdx.x;
    int v = (t < nb) ? bsum[t] : 0;
    sh[t] = v;
    __syncthreads();
    for (int off = 1; off < 512; off <<= 1) {
        int add = (t >= off) ? sh[t - off] : 0;
        __syncthreads();
        sh[t] += add;
        __syncthreads();
    }
    if (t < nb) bsum[t] = sh[t] - v;               // exclusive
}

__global__ void scan3_k(int* __restrict__ rowstart, const int* __restrict__ bsum,
                        const int* __restrict__ deg, int* __restrict__ cursor,
                        int2* __restrict__ meta, int nv) {
    int i = blockIdx.x * blockDim.x + threadIdx.x;
    if (i < nv) {
        int r = rowstart[i] + bsum[blockIdx.x];
        rowstart[i] = r;
        cursor[i]   = r;                           // place-pass allocation cursor
        meta[i]     = make_int2(r, deg[i]);
    }
}

// sliced CSR place: 8 vertex slices; block b handles spring chunk b>>3 and
// writes only endpoints in slice b&7 (round-robin pins slice<->XCD)
__global__ void place_sliced_k(const int2* __restrict__ springs,
                               const float* __restrict__ rest,
                               int* __restrict__ cursor, unsigned* __restrict__ csr,
                               int ns, int nv) {
    int b = blockIdx.x;
    int slice = b & 7;
    int s = (b >> 3) * blockDim.x + threadIdx.x;
    if (s >= ns) return;

    int lo = (int)(((long long)slice * nv) >> 3);
    int hi = (int)(((long long)(slice + 1) * nv) >> 3);

    int2 p = springs[s];
    unsigned h = __half_as_ushort(__float2half(1.0f / rest[s])) & 0x7fffu;
    if (p.x >= lo && p.x < hi)
        csr[atomicAdd(&cursor[p.x], 1)] = ((unsigned)p.y << 15) | h;
    if (p.y >= lo && p.y < hi)
        csr[atomicAdd(&cursor[p.y], 1)] = ((unsigned)p.x << 15) | h;
}

// only entry d is ever read as padding (slot1 of the boundary uint2, d odd)
__global__ void pad_k(const int2* __restrict__ meta, unsigned* __restrict__ csr,
                      int nv) {
    int v = blockIdx.x * blockDim.x + threadIdx.x;
    if (v >= nv) return;
    int2 md = meta[v];
    if (md.y > 0 && (md.y & 1)) csr[md.x + md.y] = csr[md.x];
}

// ---------- fused per-substep kernel ----------

__device__ __forceinline__ void accum(
        unsigned e, float4 g, const float4* __restrict__ Vin, float msk,
        const float4& ga, const float3& va,
        float& fx, float& fy, float& fz) {
    float invr = __uint_as_float(((e & 0x7fffu) << 13) + (112u << 23));
    float dx = g.x - ga.x, dy = g.y - ga.y, dz = g.z - ga.z;
    float3 vb = getvel(g.w, Vin, (int)(e >> 15));
    float len = sqrtf(dx * dx + dy * dy + dz * dz);
    float il = 1.0f / len;             // all entries (incl. dups) valid: len > 0
    float ddx = dx * il, ddy = dy * il, ddz = dz * il;
    float vrel = (vb.x - va.x) * ddx + (vb.y - va.y) * ddy + (vb.z - va.z) * ddz;
    float coef = (SPRING_Y * (len * invr - 1.0f) + DASHPOT * vrel) * msk;
    fx += coef * ddx;
    fy += coef * ddy;
    fz += coef * ddz;
}

__global__ void __launch_bounds__(256) substep_k(
        const float4* __restrict__ Gin, float4* __restrict__ Gout,
        const float4* __restrict__ Vin, float4* __restrict__ Vout,
        const unsigned* __restrict__ csr, const int2* __restrict__ meta,
        const float* __restrict__ mass, int nv,
        float* __restrict__ out) {
    int gid = blockIdx.x * blockDim.x + threadIdx.x;
    int vid = gid >> 3;
    int sub = gid & 7;
    if (vid >= nv) return;

    int2 md = meta[vid];               // (rowstart, deg) — one 8B load
    int d = md.y;
    float4 ga = Gin[vid];              // pos + packed vel (one line, all lanes)
    float3 va = getvel(ga.w, Vin, vid);  // quantized (or exact-sentinel) va in
                                       // force path — symmetric with vb
    int niter = (d > 2 * sub) ? ((d - 2 * sub + 15) >> 4) : 0;
    const uint2* ap = (const uint2*)(csr + md.x) + sub;

    float fx = 0.0f, fy = 0.0f, fz = 0.0f;

    for (int u = 0; u < niter; ++u) {
        uint2 q = ap[8 * u];           // lane's 2 entries: one 8B load;
                                       // wave's 8 lanes = one 64B line
        float4 g0 = Gin[(int)(q.x >> 15)];   // 1 request per eval
        float4 g1 = Gin[(int)(q.y >> 15)];
        // slot0 (even global idx) always valid inside niter
        accum(q.x, g0, Vin, 1.0f, ga, va, fx, fy, fz);
        // slot1 masked only at the odd-d boundary (reads the dup entry)
        float msk1 = (16 * u + 2 * sub + 1 < d) ? 1.0f : 0.0f;
        accum(q.y, g1, Vin, msk1, ga, va, fx, fy, fz);
    }

    // reduce across the 8 lanes of this vertex (xor stays within the group)
    fx += __shfl_xor(fx, 1);
    fx += __shfl_xor(fx, 2);
    fx += __shfl_xor(fx, 4);
    fy += __shfl_xor(fy, 1);
    fy += __shfl_xor(fy, 2);
    fy += __shfl_xor(fy, 4);
    fz += __shfl_xor(fz, 1);
    fz += __shfl_xor(fz, 2);
    fz += __shfl_xor(fz, 4);

    if (sub == 0) {
        float4 vf = Vin[vid];          // full-precision velocity state
        float m = mass[vid];
        fz += m * (-9.8f);
        float invm = 1.0f / m;

        vf.x = (vf.x + DT * fx * invm) * DRAG;
        vf.y = (vf.y + DT * fy * invm) * DRAG;
        vf.z = (vf.z + DT * fz * invm) * DRAG;

        float px = ga.x + DT * vf.x;
        float py = ga.y + DT * vf.y;
        float pz = ga.z + DT * vf.z;
        pz = fmaxf(pz, 0.0f);
        if (pz == 0.0f) vf.z = 0.0f;

        Gout[vid] = make_float4(px, py, pz, packv(vf.x, vf.y, vf.z));
        Vout[vid] = vf;

        if (out) {                     // final substep: emit packed (NV,3) output
            out[3 * vid + 0] = px;
            out[3 * vid + 1] = py;
            out[3 * vid + 2] = pz;
        }
    }
}

extern "C" void kernel_launch(void* const* d_in, const int* in_sizes, int n_in,
                              void* d_out, int out_size, void* d_ws, size_t ws_size,
                              hipStream_t stream) {
    const float* x0      = (const float*)d_in[0];   // (NV,3) fp32
    const int2*  springs = (const int2*)d_in[1];    // (NS,2) int32
    const float* rest    = (const float*)d_in[2];   // (NS,)  fp32
    const float* mass    = (const float*)d_in[3];   // (NV,)  fp32

    const int ns = in_sizes[2];        // 1,000,000
    const int nv = in_sizes[3];        // 100,000
    const int nb = (nv + 255) / 256;   // 391

    // workspace layout (~23 MB)
    char* ws = (char*)d_ws;
    size_t o = 0;
    float4* Ga    = (float4*)(ws + o); o += (size_t)nv * 16;   // pos + packed vel
    float4* Gb    = (float4*)(ws + o); o += (size_t)nv * 16;
    float4* Va    = (float4*)(ws + o); o += (size_t)nv * 16;   // fp32 vel state
    float4* Vb    = (float4*)(ws + o); o += (size_t)nv * 16;
    int* deg      = (int*)(ws + o);    o += (((size_t)nv * 4 + 15) & ~15ull);
    int* rowstart = (int*)(ws + o);    o += (((size_t)nv * 4 + 15) & ~15ull);
    int* cursor   = (int*)(ws + o);    o += (((size_t)nv * 4 + 15) & ~15ull);
    int2* meta    = (int2*)(ws + o);   o += (size_t)nv * 8;
    int* bsum     = (int*)(ws + o);    o += 512 * 4;
    o = (o + 63) & ~63ull;             // 64B-align csr (rows are 64B multiples)
    unsigned* csr = (unsigned*)(ws + o);               // <= (2M + 16*nv)*4B ~ 14.4MB

    dim3 blk(256);
    dim3 vgrid(nb);
    dim3 sgrid((ns + 255) / 256);
    dim3 pgrid(8 * ((ns + 255) / 256));            // 8 slices x spring chunks
    dim3 subgrid(((size_t)nv * 8 + 255) / 256);    // 8 lanes per vertex

    // build (replayed every call; amortized over 100 substeps)
    init_k<<<vgrid, blk, 0, stream>>>(x0, Ga, Va, deg, nv);
    count_k<<<sgrid, blk, 0, stream>>>(springs, deg, ns);
    scan1_k<<<vgrid, blk, 0, stream>>>(deg, rowstart, bsum, nv);
    scan2_k<<<dim3(1), dim3(512), 0, stream>>>(bsum, nb);
    scan3_k<<<vgrid, blk, 0, stream>>>(rowstart, bsum, deg, cursor, meta, nv);
    place_sliced_k<<<pgrid, blk, 0, stream>>>(springs, rest, cursor, csr, ns, nv);
    pad_k<<<vgrid, blk, 0, stream>>>(meta, csr, nv);

    float4* Gi = Ga; float4* Go = Gb;
    float4* Vi = Va; float4* Vo = Vb;
    for (int t = 0; t < NSUB; ++t) {
        float* out = (t == NSUB - 1) ? (float*)d_out : nullptr;
        substep_k<<<subgrid, blk, 0, stream>>>(Gi, Go, Vi, Vo, csr, meta,
                                               mass, nv, out);
        float4* tg = Gi; Gi = Go; Go = tg;
        float4* tv = Vi; Vi = Vo; Vo = tv;
    }
}